// Round 1
// baseline (636.419 us; speedup 1.0000x reference)
//
#include <hip/hip_runtime.h>
#include <cstdint>
#include <cstddef>

#define EPS 1e-5f

typedef __attribute__((ext_vector_type(4))) int int32x4;

// ---------------- block reduction helpers (256 threads = 4 waves) ----------------
__device__ __forceinline__ float blk_sum(float v, float* s4) {
    #pragma unroll
    for (int o = 32; o; o >>= 1) v += __shfl_down(v, o, 64);
    if ((threadIdx.x & 63) == 0) s4[threadIdx.x >> 6] = v;
    __syncthreads();
    v = s4[0] + s4[1] + s4[2] + s4[3];
    __syncthreads();
    return v;
}

__device__ __forceinline__ float blk_max(float v, float* s4) {
    #pragma unroll
    for (int o = 32; o; o >>= 1) v = fmaxf(v, __shfl_down(v, o, 64));
    if ((threadIdx.x & 63) == 0) s4[threadIdx.x >> 6] = v;
    __syncthreads();
    v = fmaxf(fmaxf(s4[0], s4[1]), fmaxf(s4[2], s4[3]));
    __syncthreads();
    return v;
}

__device__ __forceinline__ int pack4(float a, float b, float c, float d, float lo, float hi) {
    int x0 = (int)fminf(fmaxf(a, lo), hi);
    int x1 = (int)fminf(fmaxf(b, lo), hi);
    int x2 = (int)fminf(fmaxf(c, lo), hi);
    int x3 = (int)fminf(fmaxf(d, lo), hi);
    return (x0 & 255) | ((x1 & 255) << 8) | ((x2 & 255) << 16) | ((x3 & 255) << 24);
}

// ---------------- weight absmean: sum(|w|) -> atomicAdd into out ----------------
__global__ __launch_bounds__(256) void absmean_kernel(const float* __restrict__ w,
                                                      long long n4, float* __restrict__ out) {
    __shared__ float s4[4];
    const float4* w4 = (const float4*)w;
    float s = 0.f;
    for (long long i = (long long)blockIdx.x * 256 + threadIdx.x; i < n4;
         i += (long long)gridDim.x * 256) {
        float4 v = w4[i];
        s += fabsf(v.x) + fabsf(v.y) + fabsf(v.z) + fabsf(v.w);
    }
    s = blk_sum(s, s4);
    if (threadIdx.x == 0) atomicAdd(out, s);
}

// ---------------- ternary weight quantization ----------------
__global__ __launch_bounds__(256) void wquant_kernel(const float* __restrict__ w,
                                                     int* __restrict__ q, long long n4,
                                                     const float* __restrict__ sump, float invN) {
    float mean = fmaxf(sump[0] * invN, EPS);
    float scale = 1.f / mean;
    const float4* w4 = (const float4*)w;
    for (long long i = (long long)blockIdx.x * 256 + threadIdx.x; i < n4;
         i += (long long)gridDim.x * 256) {
        float4 v = w4[i];
        q[i] = pack4(rintf(v.x * scale), rintf(v.y * scale),
                     rintf(v.z * scale), rintf(v.w * scale), -1.f, 1.f);
    }
}

// ---------------- input activation quantization (D = 1024) ----------------
__global__ __launch_bounds__(256) void actquant_kernel(const float* __restrict__ x,
                                                       int* __restrict__ q,
                                                       float* __restrict__ inv_s) {
    __shared__ float s4[4];
    int row = blockIdx.x;
    const float4* xr = (const float4*)(x + (size_t)row * 1024);
    float4 v = xr[threadIdx.x];
    float m = fmaxf(fmaxf(fabsf(v.x), fabsf(v.y)), fmaxf(fabsf(v.z), fabsf(v.w)));
    m = blk_max(m, s4);
    m = fmaxf(m, EPS);
    float scale = 127.f / m;
    if (threadIdx.x == 0) inv_s[row] = m / 127.f;
    q[(size_t)row * 256 + threadIdx.x] =
        pack4(rintf(v.x * scale), rintf(v.y * scale),
              rintf(v.z * scale), rintf(v.w * scale), -128.f, 127.f);
}

// ---------------- fused LayerNorm + SiLU + act quant (H = 4096) ----------------
__global__ __launch_bounds__(256) void ln_silu_quant_kernel(const float* __restrict__ h,
                                                            const float* __restrict__ g,
                                                            const float* __restrict__ b,
                                                            int* __restrict__ q,
                                                            float* __restrict__ inv_s) {
    __shared__ float s4[4];
    int row = blockIdx.x;
    const float4* xr = (const float4*)(h + (size_t)row * 4096);
    float4 v[4];
    float sum = 0.f, sq = 0.f;
    #pragma unroll
    for (int i = 0; i < 4; i++) {
        v[i] = xr[threadIdx.x + i * 256];
        sum += v[i].x + v[i].y + v[i].z + v[i].w;
        sq += v[i].x * v[i].x + v[i].y * v[i].y + v[i].z * v[i].z + v[i].w * v[i].w;
    }
    sum = blk_sum(sum, s4);
    sq = blk_sum(sq, s4);
    float mu = sum * (1.f / 4096.f);
    float var = sq * (1.f / 4096.f) - mu * mu;
    float rs = rsqrtf(var + EPS);
    const float4* g4 = (const float4*)g;
    const float4* b4 = (const float4*)b;
    float amax = 0.f;
    #pragma unroll
    for (int i = 0; i < 4; i++) {
        float4 gg = g4[threadIdx.x + i * 256];
        float4 bb = b4[threadIdx.x + i * 256];
        float y0 = (v[i].x - mu) * rs * gg.x + bb.x;
        float y1 = (v[i].y - mu) * rs * gg.y + bb.y;
        float y2 = (v[i].z - mu) * rs * gg.z + bb.z;
        float y3 = (v[i].w - mu) * rs * gg.w + bb.w;
        v[i].x = y0 / (1.f + expf(-y0));
        v[i].y = y1 / (1.f + expf(-y1));
        v[i].z = y2 / (1.f + expf(-y2));
        v[i].w = y3 / (1.f + expf(-y3));
        amax = fmaxf(amax, fmaxf(fmaxf(fabsf(v[i].x), fabsf(v[i].y)),
                                 fmaxf(fabsf(v[i].z), fabsf(v[i].w))));
    }
    amax = blk_max(amax, s4);
    amax = fmaxf(amax, EPS);
    float scale = 127.f / amax;
    if (threadIdx.x == 0) inv_s[row] = amax / 127.f;
    #pragma unroll
    for (int i = 0; i < 4; i++) {
        q[(size_t)row * 1024 + threadIdx.x + i * 256] =
            pack4(rintf(v[i].x * scale), rintf(v[i].y * scale),
                  rintf(v[i].z * scale), rintf(v[i].w * scale), -128.f, 127.f);
    }
}

// ---------------- i8 MFMA GEMM: C[b,o] = sum_k A[b,k]*B[o,k] ----------------
// 128x128 tile, BK=64, 4 waves each computing a 64x64 quadrant (4x4 of 16x16x64).
__device__ __forceinline__ void load_lds16(const void* g, void* l) {
    __builtin_amdgcn_global_load_lds((__attribute__((address_space(1))) void*)(g),
                                     (__attribute__((address_space(3))) void*)(l), 16, 0, 0);
}

template <int MODE>  // 0: write fp32 h[gr*4096+gc]; 1: final sigmoid epilogue into d_out
__global__ __launch_bounds__(256, 2) void gemm_i8_kernel(
    const char* __restrict__ A, const char* __restrict__ B,
    const float* __restrict__ inv_s, const float* __restrict__ wsum, float invWN,
    int K, float* __restrict__ out) {
    __shared__ __align__(16) char lA[128 * 64];
    __shared__ __align__(16) char lB[128 * 64];
    const int t = threadIdx.x;
    const int lane = t & 63;
    const int wave = t >> 6;
    const int bm = blockIdx.y * 128, bn = blockIdx.x * 128;
    const int wr = (wave >> 1) * 64, wc = (wave & 1) * 64;

    int32x4 acc[4][4] = {};

    // staging addresses: linear byte bi = i*4096 + t*16; row = bi/64, col = bi%64
    const int r0 = t >> 2;           // (t*16)/64
    const int c0 = (t & 3) * 16;     // (t*16)%64
    const char* gA0 = A + (size_t)(bm + r0) * K + c0;
    const char* gA1 = A + (size_t)(bm + r0 + 64) * K + c0;
    const char* gB0 = B + (size_t)(bn + r0) * K + c0;
    const char* gB1 = B + (size_t)(bn + r0 + 64) * K + c0;
    char* sA0 = lA + t * 16;
    char* sA1 = lA + 4096 + t * 16;
    char* sB0 = lB + t * 16;
    char* sB1 = lB + 4096 + t * 16;

    const int fr = lane & 15;
    const int fq = lane >> 4;

    for (int k0 = 0; k0 < K; k0 += 64) {
        load_lds16(gA0 + k0, sA0);
        load_lds16(gA1 + k0, sA1);
        load_lds16(gB0 + k0, sB0);
        load_lds16(gB1 + k0, sB1);
        __syncthreads();

        int32x4 af[4], bf[4];
        #pragma unroll
        for (int mt = 0; mt < 4; mt++)
            af[mt] = *(const int32x4*)(lA + (wr + mt * 16 + fr) * 64 + fq * 16);
        #pragma unroll
        for (int nt = 0; nt < 4; nt++)
            bf[nt] = *(const int32x4*)(lB + (wc + nt * 16 + fr) * 64 + fq * 16);
        #pragma unroll
        for (int mt = 0; mt < 4; mt++) {
            #pragma unroll
            for (int nt = 0; nt < 4; nt++) {
                acc[mt][nt] =
                    __builtin_amdgcn_mfma_i32_16x16x64_i8(af[mt], bf[nt], acc[mt][nt], 0, 0, 0);
            }
        }
        __syncthreads();
    }

    // epilogue: C/D layout col = lane&15, row = (lane>>4)*4 + reg
    const float wmean = fmaxf(wsum[0] * invWN, EPS);
    #pragma unroll
    for (int mt = 0; mt < 4; mt++) {
        #pragma unroll
        for (int rg = 0; rg < 4; rg++) {
            int gr = bm + wr + mt * 16 + fq * 4 + rg;
            float rowscale = inv_s[gr] * wmean;
            #pragma unroll
            for (int nt = 0; nt < 4; nt++) {
                int gc = bn + wc + nt * 16 + fr;
                float v = (float)acc[mt][nt][rg] * rowscale;
                if (MODE == 0) {
                    out[(size_t)gr * 4096 + gc] = v;
                } else {
                    if (gc < 2000) {
                        float sg = 1.f / (1.f + expf(-v));
                        if (gc < 1000)
                            out[(size_t)gr * 1000 + gc] = sg * 999.f + 1.f;
                        else
                            out[(size_t)4096 * 1000 + (size_t)gr * 1000 + (gc - 1000)] =
                                sg * 100.f;
                    }
                }
            }
        }
    }
}

// ---------------- host launcher ----------------
extern "C" void kernel_launch(void* const* d_in, const int* in_sizes, int n_in,
                              void* d_out, int out_size, void* d_ws, size_t ws_size,
                              hipStream_t stream) {
    const float* x  = (const float*)d_in[0];
    const float* W0 = (const float*)d_in[1];
    const float* W1 = (const float*)d_in[2];
    const float* W2 = (const float*)d_in[3];
    const float* W3 = (const float*)d_in[4];
    const float* g0 = (const float*)d_in[5];
    const float* b0 = (const float*)d_in[6];
    const float* g1 = (const float*)d_in[7];
    const float* b1 = (const float*)d_in[8];
    const float* g2 = (const float*)d_in[9];
    const float* b2 = (const float*)d_in[10];
    float* out = (float*)d_out;

    char* ws = (char*)d_ws;
    size_t off = 0;
    auto alloc = [&](size_t bytes) -> char* {
        char* p = ws + off;
        off = (off + bytes + 255) & ~(size_t)255;
        return p;
    };
    float* sums = (float*)alloc(4 * sizeof(float));
    float* inv0 = (float*)alloc(4096 * 4);
    float* inv1 = (float*)alloc(4096 * 4);
    float* inv2 = (float*)alloc(4096 * 4);
    float* inv3 = (float*)alloc(4096 * 4);
    char* wq0 = alloc(4096ll * 1024);
    char* wq1 = alloc(4096ll * 4096);
    char* wq2 = alloc(4096ll * 4096);
    char* wq3 = alloc(2048ll * 4096);   // padded to 2048 rows
    char* a0  = alloc(4096ll * 1024);
    char* a1  = alloc(4096ll * 4096);
    char* a2  = alloc(4096ll * 4096);
    float* h  = (float*)alloc(4096ll * 4096 * 4);
    char* a3 = a1;  // a1 dead after GEMM1; safe sequential reuse

    const long long n0 = 4096ll * 1024, n1 = 4096ll * 4096, n2 = 4096ll * 4096,
                    n3 = 2000ll * 4096;

    hipMemsetAsync(sums, 0, 4 * sizeof(float), stream);
    hipMemsetAsync(wq3, 0, 2048ll * 4096, stream);

    absmean_kernel<<<1024, 256, 0, stream>>>(W0, n0 / 4, sums + 0);
    absmean_kernel<<<2048, 256, 0, stream>>>(W1, n1 / 4, sums + 1);
    absmean_kernel<<<2048, 256, 0, stream>>>(W2, n2 / 4, sums + 2);
    absmean_kernel<<<1024, 256, 0, stream>>>(W3, n3 / 4, sums + 3);

    wquant_kernel<<<1024, 256, 0, stream>>>(W0, (int*)wq0, n0 / 4, sums + 0, 1.f / (float)n0);
    wquant_kernel<<<2048, 256, 0, stream>>>(W1, (int*)wq1, n1 / 4, sums + 1, 1.f / (float)n1);
    wquant_kernel<<<2048, 256, 0, stream>>>(W2, (int*)wq2, n2 / 4, sums + 2, 1.f / (float)n2);
    wquant_kernel<<<1024, 256, 0, stream>>>(W3, (int*)wq3, n3 / 4, sums + 3, 1.f / (float)n3);

    actquant_kernel<<<4096, 256, 0, stream>>>(x, (int*)a0, inv0);

    gemm_i8_kernel<0><<<dim3(32, 32), 256, 0, stream>>>(a0, wq0, inv0, sums + 0,
                                                        1.f / (float)n0, 1024, h);
    ln_silu_quant_kernel<<<4096, 256, 0, stream>>>(h, g0, b0, (int*)a1, inv1);

    gemm_i8_kernel<0><<<dim3(32, 32), 256, 0, stream>>>(a1, wq1, inv1, sums + 1,
                                                        1.f / (float)n1, 4096, h);
    ln_silu_quant_kernel<<<4096, 256, 0, stream>>>(h, g1, b1, (int*)a2, inv2);

    gemm_i8_kernel<0><<<dim3(32, 32), 256, 0, stream>>>(a2, wq2, inv2, sums + 2,
                                                        1.f / (float)n2, 4096, h);
    ln_silu_quant_kernel<<<4096, 256, 0, stream>>>(h, g2, b2, (int*)a3, inv3);

    gemm_i8_kernel<1><<<dim3(16, 32), 256, 0, stream>>>(a3, wq3, inv3, sums + 3,
                                                        1.f / (float)n3, 4096, out);
}

// Round 2
// 612.385 us; speedup vs baseline: 1.0392x; 1.0392x over previous
//
#include <hip/hip_runtime.h>
#include <hip/hip_bf16.h>
#include <cstdint>
#include <cstddef>

#define EPS 1e-5f

typedef __attribute__((ext_vector_type(4))) int int32x4;
typedef __attribute__((ext_vector_type(16))) int int32x16;

// ---------------- block reduction helpers (256 threads = 4 waves) ----------------
__device__ __forceinline__ float blk_sum(float v, float* s4) {
    #pragma unroll
    for (int o = 32; o; o >>= 1) v += __shfl_down(v, o, 64);
    if ((threadIdx.x & 63) == 0) s4[threadIdx.x >> 6] = v;
    __syncthreads();
    v = s4[0] + s4[1] + s4[2] + s4[3];
    __syncthreads();
    return v;
}

__device__ __forceinline__ void blk_sum2(float& a, float& b, float* s8) {
    #pragma unroll
    for (int o = 32; o; o >>= 1) {
        a += __shfl_down(a, o, 64);
        b += __shfl_down(b, o, 64);
    }
    if ((threadIdx.x & 63) == 0) {
        s8[threadIdx.x >> 6] = a;
        s8[4 + (threadIdx.x >> 6)] = b;
    }
    __syncthreads();
    a = s8[0] + s8[1] + s8[2] + s8[3];
    b = s8[4] + s8[5] + s8[6] + s8[7];
    __syncthreads();
}

__device__ __forceinline__ float blk_max(float v, float* s4) {
    #pragma unroll
    for (int o = 32; o; o >>= 1) v = fmaxf(v, __shfl_down(v, o, 64));
    if ((threadIdx.x & 63) == 0) s4[threadIdx.x >> 6] = v;
    __syncthreads();
    v = fmaxf(fmaxf(s4[0], s4[1]), fmaxf(s4[2], s4[3]));
    __syncthreads();
    return v;
}

__device__ __forceinline__ int pack4(float a, float b, float c, float d, float lo, float hi) {
    int x0 = (int)fminf(fmaxf(a, lo), hi);
    int x1 = (int)fminf(fmaxf(b, lo), hi);
    int x2 = (int)fminf(fmaxf(c, lo), hi);
    int x3 = (int)fminf(fmaxf(d, lo), hi);
    return (x0 & 255) | ((x1 & 255) << 8) | ((x2 & 255) << 16) | ((x3 & 255) << 24);
}

__device__ __forceinline__ float bflo(unsigned u) { return __uint_as_float(u << 16); }
__device__ __forceinline__ float bfhi(unsigned u) { return __uint_as_float(u & 0xffff0000u); }

// ---------------- fused absmean over all 4 weights (1 launch) ----------------
__global__ __launch_bounds__(256) void absmean_all_kernel(
    const float* __restrict__ W0, const float* __restrict__ W1,
    const float* __restrict__ W2, const float* __restrict__ W3,
    float* __restrict__ sums) {
    __shared__ float s4[4];
    const float* w; long long n4; int sidx, nb, lb;
    int bx = blockIdx.x;
    if (bx < 1024)      { w = W0; n4 = 1048576;  sidx = 0; nb = 1024; lb = bx; }
    else if (bx < 3072) { w = W1; n4 = 4194304;  sidx = 1; nb = 2048; lb = bx - 1024; }
    else if (bx < 5120) { w = W2; n4 = 4194304;  sidx = 2; nb = 2048; lb = bx - 3072; }
    else                { w = W3; n4 = 2048000;  sidx = 3; nb = 1024; lb = bx - 5120; }
    const float4* w4 = (const float4*)w;
    float s = 0.f;
    for (long long i = (long long)lb * 256 + threadIdx.x; i < n4; i += (long long)nb * 256) {
        float4 v = w4[i];
        s += fabsf(v.x) + fabsf(v.y) + fabsf(v.z) + fabsf(v.w);
    }
    s = blk_sum(s, s4);
    if (threadIdx.x == 0) atomicAdd(&sums[sidx], s);
}

// ---------------- fused ternary quantization for all 4 weights + W3 pad ----------------
__global__ __launch_bounds__(256) void wquant_all_kernel(
    const float* __restrict__ W0, const float* __restrict__ W1,
    const float* __restrict__ W2, const float* __restrict__ W3,
    int* __restrict__ q0, int* __restrict__ q1, int* __restrict__ q2, int* __restrict__ q3,
    const float* __restrict__ sums) {
    const float* w; int* q; long long n4, pn4; int sidx, nb, lb; float invN;
    int bx = blockIdx.x;
    if (bx < 1024)      { w = W0; q = q0; n4 = 1048576;  pn4 = 1048576; sidx = 0; nb = 1024; lb = bx;        invN = 1.f / 4194304.f; }
    else if (bx < 3072) { w = W1; q = q1; n4 = 4194304;  pn4 = 4194304; sidx = 1; nb = 2048; lb = bx - 1024; invN = 1.f / 16777216.f; }
    else if (bx < 5120) { w = W2; q = q2; n4 = 4194304;  pn4 = 4194304; sidx = 2; nb = 2048; lb = bx - 3072; invN = 1.f / 16777216.f; }
    else                { w = W3; q = q3; n4 = 2048000;  pn4 = 2097152; sidx = 3; nb = 1024; lb = bx - 5120; invN = 1.f / 8192000.f; }
    float mean = fmaxf(sums[sidx] * invN, EPS);
    float scale = 1.f / mean;
    const float4* w4 = (const float4*)w;
    for (long long i = (long long)lb * 256 + threadIdx.x; i < pn4; i += (long long)nb * 256) {
        if (i < n4) {
            float4 v = w4[i];
            q[i] = pack4(rintf(v.x * scale), rintf(v.y * scale),
                         rintf(v.z * scale), rintf(v.w * scale), -1.f, 1.f);
        } else {
            q[i] = 0;  // zero-pad W3 rows 2000..2047
        }
    }
}

// ---------------- input activation quantization (D = 1024) ----------------
__global__ __launch_bounds__(256) void actquant_kernel(const float* __restrict__ x,
                                                       int* __restrict__ q,
                                                       float* __restrict__ inv_s) {
    __shared__ float s4[4];
    int row = blockIdx.x;
    const float4* xr = (const float4*)(x + (size_t)row * 1024);
    float4 v = xr[threadIdx.x];
    float m = fmaxf(fmaxf(fabsf(v.x), fabsf(v.y)), fmaxf(fabsf(v.z), fabsf(v.w)));
    m = blk_max(m, s4);
    m = fmaxf(m, EPS);
    float scale = 127.f / m;
    if (threadIdx.x == 0) inv_s[row] = m / 127.f;
    q[(size_t)row * 256 + threadIdx.x] =
        pack4(rintf(v.x * scale), rintf(v.y * scale),
              rintf(v.z * scale), rintf(v.w * scale), -128.f, 127.f);
}

// ---------------- fused LayerNorm + SiLU + act quant, bf16 input (H = 4096) ------------
__global__ __launch_bounds__(256) void ln_silu_quant_kernel(const ushort* __restrict__ h,
                                                            const float* __restrict__ g,
                                                            const float* __restrict__ b,
                                                            int* __restrict__ q,
                                                            float* __restrict__ inv_s) {
    __shared__ float s8[8];
    int row = blockIdx.x;
    int t = threadIdx.x;
    const uint4* hr = (const uint4*)(h + (size_t)row * 4096);
    uint4 p0 = hr[t * 2], p1 = hr[t * 2 + 1];  // 16 bf16 elems per thread
    float f[16];
    f[0] = bflo(p0.x); f[1] = bfhi(p0.x); f[2] = bflo(p0.y); f[3] = bfhi(p0.y);
    f[4] = bflo(p0.z); f[5] = bfhi(p0.z); f[6] = bflo(p0.w); f[7] = bfhi(p0.w);
    f[8] = bflo(p1.x); f[9] = bfhi(p1.x); f[10] = bflo(p1.y); f[11] = bfhi(p1.y);
    f[12] = bflo(p1.z); f[13] = bfhi(p1.z); f[14] = bflo(p1.w); f[15] = bfhi(p1.w);
    float sum = 0.f, sq = 0.f;
    #pragma unroll
    for (int i = 0; i < 16; i++) { sum += f[i]; sq += f[i] * f[i]; }
    blk_sum2(sum, sq, s8);
    float mu = sum * (1.f / 4096.f);
    float var = sq * (1.f / 4096.f) - mu * mu;
    float rs = rsqrtf(var + EPS);
    const float4* g4 = (const float4*)g;
    const float4* b4 = (const float4*)b;
    float amax = 0.f;
    #pragma unroll
    for (int i = 0; i < 4; i++) {
        float4 gg = g4[t * 4 + i];
        float4 bb = b4[t * 4 + i];
        float y0 = (f[i * 4 + 0] - mu) * rs * gg.x + bb.x;
        float y1 = (f[i * 4 + 1] - mu) * rs * gg.y + bb.y;
        float y2 = (f[i * 4 + 2] - mu) * rs * gg.z + bb.z;
        float y3 = (f[i * 4 + 3] - mu) * rs * gg.w + bb.w;
        f[i * 4 + 0] = y0 / (1.f + expf(-y0));
        f[i * 4 + 1] = y1 / (1.f + expf(-y1));
        f[i * 4 + 2] = y2 / (1.f + expf(-y2));
        f[i * 4 + 3] = y3 / (1.f + expf(-y3));
    }
    #pragma unroll
    for (int i = 0; i < 16; i++) amax = fmaxf(amax, fabsf(f[i]));
    amax = blk_max(amax, s8);
    amax = fmaxf(amax, EPS);
    float scale = 127.f / amax;
    if (t == 0) inv_s[row] = amax / 127.f;
    int4 o;
    o.x = pack4(rintf(f[0] * scale), rintf(f[1] * scale), rintf(f[2] * scale), rintf(f[3] * scale), -128.f, 127.f);
    o.y = pack4(rintf(f[4] * scale), rintf(f[5] * scale), rintf(f[6] * scale), rintf(f[7] * scale), -128.f, 127.f);
    o.z = pack4(rintf(f[8] * scale), rintf(f[9] * scale), rintf(f[10] * scale), rintf(f[11] * scale), -128.f, 127.f);
    o.w = pack4(rintf(f[12] * scale), rintf(f[13] * scale), rintf(f[14] * scale), rintf(f[15] * scale), -128.f, 127.f);
    ((int4*)((char*)q + (size_t)row * 4096))[t] = o;
}

// ---------------- i8 MFMA GEMM: C[b,o] = sum_k A[b,k]*B[o,k] ----------------
// 128x128 tile, BK=64, 4 waves each computing a 64x64 quadrant (2x2 of 32x32x32).
__device__ __forceinline__ void load_lds16(const void* g, void* l) {
    __builtin_amdgcn_global_load_lds((__attribute__((address_space(1))) void*)(g),
                                     (__attribute__((address_space(3))) void*)(l), 16, 0, 0);
}

template <int MODE>  // 0: write bf16 h[gr*4096+gc]; 1: final sigmoid epilogue into d_out
__global__ __launch_bounds__(256, 4) void gemm_i8_kernel(
    const char* __restrict__ A, const char* __restrict__ B,
    const float* __restrict__ inv_s, const float* __restrict__ wsum, float invWN,
    int K, void* __restrict__ outp) {
    __shared__ __align__(16) char lA[128 * 64];
    __shared__ __align__(16) char lB[128 * 64];
    const int t = threadIdx.x;
    const int lane = t & 63;
    const int wave = t >> 6;
    const int bm = blockIdx.y * 128, bn = blockIdx.x * 128;
    const int wr = (wave >> 1) * 64, wc = (wave & 1) * 64;

    int32x16 acc[2][2] = {};

    // staging: linear byte bi = half*4096 + t*16; row = bi/64, col = bi%64
    const int r0 = t >> 2;
    const int c0 = (t & 3) * 16;
    const char* gA0 = A + (size_t)(bm + r0) * K + c0;
    const char* gA1 = A + (size_t)(bm + r0 + 64) * K + c0;
    const char* gB0 = B + (size_t)(bn + r0) * K + c0;
    const char* gB1 = B + (size_t)(bn + r0 + 64) * K + c0;
    char* sA0 = lA + t * 16;
    char* sA1 = lA + 4096 + t * 16;
    char* sB0 = lB + t * 16;
    char* sB1 = lB + 4096 + t * 16;

    const int r = lane & 31;   // mfma row/col within 32
    const int q = lane >> 5;   // k-half selector
    const char* pA0 = lA + (wr + r) * 64 + q * 16;
    const char* pA1 = pA0 + 32 * 64;
    const char* pB0 = lB + (wc + r) * 64 + q * 16;
    const char* pB1 = pB0 + 32 * 64;

    for (int k0 = 0; k0 < K; k0 += 64) {
        load_lds16(gA0 + k0, sA0);
        load_lds16(gA1 + k0, sA1);
        load_lds16(gB0 + k0, sB0);
        load_lds16(gB1 + k0, sB1);
        __syncthreads();

        #pragma unroll
        for (int ks = 0; ks < 2; ks++) {
            int32x4 a0 = *(const int32x4*)(pA0 + ks * 32);
            int32x4 a1 = *(const int32x4*)(pA1 + ks * 32);
            int32x4 b0 = *(const int32x4*)(pB0 + ks * 32);
            int32x4 b1 = *(const int32x4*)(pB1 + ks * 32);
            acc[0][0] = __builtin_amdgcn_mfma_i32_32x32x32_i8(a0, b0, acc[0][0], 0, 0, 0);
            acc[0][1] = __builtin_amdgcn_mfma_i32_32x32x32_i8(a0, b1, acc[0][1], 0, 0, 0);
            acc[1][0] = __builtin_amdgcn_mfma_i32_32x32x32_i8(a1, b0, acc[1][0], 0, 0, 0);
            acc[1][1] = __builtin_amdgcn_mfma_i32_32x32x32_i8(a1, b1, acc[1][1], 0, 0, 0);
        }
        __syncthreads();
    }

    // epilogue: C/D layout col = lane&31, row = (reg&3) + 8*(reg>>2) + 4*(lane>>5)
    const float wmean = fmaxf(wsum[0] * invWN, EPS);
    #pragma unroll
    for (int mt = 0; mt < 2; mt++) {
        #pragma unroll
        for (int reg = 0; reg < 16; reg++) {
            int gr = bm + wr + mt * 32 + 4 * q + (reg & 3) + 8 * (reg >> 2);
            float rowscale = inv_s[gr] * wmean;
            #pragma unroll
            for (int nt = 0; nt < 2; nt++) {
                int gc = bn + wc + nt * 32 + r;
                float v = (float)acc[mt][nt][reg] * rowscale;
                if (MODE == 0) {
                    ((__hip_bfloat16*)outp)[(size_t)gr * 4096 + gc] = __float2bfloat16(v);
                } else {
                    if (gc < 2000) {
                        float sg = 1.f / (1.f + expf(-v));
                        float* out = (float*)outp;
                        if (gc < 1000)
                            out[(size_t)gr * 1000 + gc] = sg * 999.f + 1.f;
                        else
                            out[(size_t)4096 * 1000 + (size_t)gr * 1000 + (gc - 1000)] =
                                sg * 100.f;
                    }
                }
            }
        }
    }
}

// ---------------- host launcher ----------------
extern "C" void kernel_launch(void* const* d_in, const int* in_sizes, int n_in,
                              void* d_out, int out_size, void* d_ws, size_t ws_size,
                              hipStream_t stream) {
    const float* x  = (const float*)d_in[0];
    const float* W0 = (const float*)d_in[1];
    const float* W1 = (const float*)d_in[2];
    const float* W2 = (const float*)d_in[3];
    const float* W3 = (const float*)d_in[4];
    const float* g0 = (const float*)d_in[5];
    const float* b0 = (const float*)d_in[6];
    const float* g1 = (const float*)d_in[7];
    const float* b1 = (const float*)d_in[8];
    const float* g2 = (const float*)d_in[9];
    const float* b2 = (const float*)d_in[10];
    float* out = (float*)d_out;

    char* ws = (char*)d_ws;
    size_t off = 0;
    auto alloc = [&](size_t bytes) -> char* {
        char* p = ws + off;
        off = (off + bytes + 255) & ~(size_t)255;
        return p;
    };
    float* sums = (float*)alloc(4 * sizeof(float));
    float* inv0 = (float*)alloc(4096 * 4);
    float* inv1 = (float*)alloc(4096 * 4);
    float* inv2 = (float*)alloc(4096 * 4);
    float* inv3 = (float*)alloc(4096 * 4);
    char* wq0 = alloc(4096ll * 1024);
    char* wq1 = alloc(4096ll * 4096);
    char* wq2 = alloc(4096ll * 4096);
    char* wq3 = alloc(2048ll * 4096);   // padded to 2048 rows
    char* a0  = alloc(4096ll * 1024);
    char* a1  = alloc(4096ll * 4096);
    char* a2  = alloc(4096ll * 4096);
    char* h   = alloc(4096ll * 4096 * 2);  // bf16 intermediate
    char* a3 = a1;  // a1 dead after GEMM1; safe sequential reuse

    hipMemsetAsync(sums, 0, 4 * sizeof(float), stream);

    absmean_all_kernel<<<6144, 256, 0, stream>>>(W0, W1, W2, W3, sums);
    actquant_kernel<<<4096, 256, 0, stream>>>(x, (int*)a0, inv0);
    wquant_all_kernel<<<6144, 256, 0, stream>>>(W0, W1, W2, W3, (int*)wq0, (int*)wq1,
                                                (int*)wq2, (int*)wq3, sums);

    gemm_i8_kernel<0><<<dim3(32, 32), 256, 0, stream>>>(a0, wq0, inv0, sums + 0,
                                                        1.f / 4194304.f, 1024, h);
    ln_silu_quant_kernel<<<4096, 256, 0, stream>>>((const ushort*)h, g0, b0, (int*)a1, inv1);

    gemm_i8_kernel<0><<<dim3(32, 32), 256, 0, stream>>>(a1, wq1, inv1, sums + 1,
                                                        1.f / 16777216.f, 4096, h);
    ln_silu_quant_kernel<<<4096, 256, 0, stream>>>((const ushort*)h, g1, b1, (int*)a2, inv2);

    gemm_i8_kernel<0><<<dim3(32, 32), 256, 0, stream>>>(a2, wq2, inv2, sums + 2,
                                                        1.f / 16777216.f, 4096, h);
    ln_silu_quant_kernel<<<4096, 256, 0, stream>>>((const ushort*)h, g2, b2, (int*)a3, inv3);

    gemm_i8_kernel<1><<<dim3(16, 32), 256, 0, stream>>>(a3, wq3, inv3, sums + 3,
                                                        1.f / 8192000.f, 4096, out);
}

// Round 3
// 545.192 us; speedup vs baseline: 1.1673x; 1.1232x over previous
//
#include <hip/hip_runtime.h>
#include <hip/hip_bf16.h>
#include <cstdint>
#include <cstddef>

#define EPS 1e-5f

typedef __attribute__((ext_vector_type(4))) int int32x4;

// ---------------- block reduction helpers (256 threads = 4 waves) ----------------
__device__ __forceinline__ float blk_sum(float v, float* s4) {
    #pragma unroll
    for (int o = 32; o; o >>= 1) v += __shfl_down(v, o, 64);
    if ((threadIdx.x & 63) == 0) s4[threadIdx.x >> 6] = v;
    __syncthreads();
    v = s4[0] + s4[1] + s4[2] + s4[3];
    __syncthreads();
    return v;
}

__device__ __forceinline__ void blk_sum2(float& a, float& b, float* s8) {
    #pragma unroll
    for (int o = 32; o; o >>= 1) {
        a += __shfl_down(a, o, 64);
        b += __shfl_down(b, o, 64);
    }
    if ((threadIdx.x & 63) == 0) {
        s8[threadIdx.x >> 6] = a;
        s8[4 + (threadIdx.x >> 6)] = b;
    }
    __syncthreads();
    a = s8[0] + s8[1] + s8[2] + s8[3];
    b = s8[4] + s8[5] + s8[6] + s8[7];
    __syncthreads();
}

__device__ __forceinline__ float blk_max(float v, float* s4) {
    #pragma unroll
    for (int o = 32; o; o >>= 1) v = fmaxf(v, __shfl_down(v, o, 64));
    if ((threadIdx.x & 63) == 0) s4[threadIdx.x >> 6] = v;
    __syncthreads();
    v = fmaxf(fmaxf(s4[0], s4[1]), fmaxf(s4[2], s4[3]));
    __syncthreads();
    return v;
}

__device__ __forceinline__ int pack4(float a, float b, float c, float d, float lo, float hi) {
    int x0 = (int)fminf(fmaxf(a, lo), hi);
    int x1 = (int)fminf(fmaxf(b, lo), hi);
    int x2 = (int)fminf(fmaxf(c, lo), hi);
    int x3 = (int)fminf(fmaxf(d, lo), hi);
    return (x0 & 255) | ((x1 & 255) << 8) | ((x2 & 255) << 16) | ((x3 & 255) << 24);
}

__device__ __forceinline__ float bflo(unsigned u) { return __uint_as_float(u << 16); }
__device__ __forceinline__ float bfhi(unsigned u) { return __uint_as_float(u & 0xffff0000u); }

// ---------------- fused absmean over all 4 weights (1 launch) ----------------
__global__ __launch_bounds__(256) void absmean_all_kernel(
    const float* __restrict__ W0, const float* __restrict__ W1,
    const float* __restrict__ W2, const float* __restrict__ W3,
    float* __restrict__ sums) {
    __shared__ float s4[4];
    const float* w; long long n4; int sidx, nb, lb;
    int bx = blockIdx.x;
    if (bx < 1024)      { w = W0; n4 = 1048576;  sidx = 0; nb = 1024; lb = bx; }
    else if (bx < 3072) { w = W1; n4 = 4194304;  sidx = 1; nb = 2048; lb = bx - 1024; }
    else if (bx < 5120) { w = W2; n4 = 4194304;  sidx = 2; nb = 2048; lb = bx - 3072; }
    else                { w = W3; n4 = 2048000;  sidx = 3; nb = 1024; lb = bx - 5120; }
    const float4* w4 = (const float4*)w;
    float s = 0.f;
    for (long long i = (long long)lb * 256 + threadIdx.x; i < n4; i += (long long)nb * 256) {
        float4 v = w4[i];
        s += fabsf(v.x) + fabsf(v.y) + fabsf(v.z) + fabsf(v.w);
    }
    s = blk_sum(s, s4);
    if (threadIdx.x == 0) atomicAdd(&sums[sidx], s);
}

// ---------------- fused ternary quantization for all 4 weights + W3 pad ----------------
__global__ __launch_bounds__(256) void wquant_all_kernel(
    const float* __restrict__ W0, const float* __restrict__ W1,
    const float* __restrict__ W2, const float* __restrict__ W3,
    int* __restrict__ q0, int* __restrict__ q1, int* __restrict__ q2, int* __restrict__ q3,
    const float* __restrict__ sums) {
    const float* w; int* q; long long n4, pn4; int sidx, nb, lb; float invN;
    int bx = blockIdx.x;
    if (bx < 1024)      { w = W0; q = q0; n4 = 1048576;  pn4 = 1048576; sidx = 0; nb = 1024; lb = bx;        invN = 1.f / 4194304.f; }
    else if (bx < 3072) { w = W1; q = q1; n4 = 4194304;  pn4 = 4194304; sidx = 1; nb = 2048; lb = bx - 1024; invN = 1.f / 16777216.f; }
    else if (bx < 5120) { w = W2; q = q2; n4 = 4194304;  pn4 = 4194304; sidx = 2; nb = 2048; lb = bx - 3072; invN = 1.f / 16777216.f; }
    else                { w = W3; q = q3; n4 = 2048000;  pn4 = 2097152; sidx = 3; nb = 1024; lb = bx - 5120; invN = 1.f / 8192000.f; }
    float mean = fmaxf(sums[sidx] * invN, EPS);
    float scale = 1.f / mean;
    const float4* w4 = (const float4*)w;
    for (long long i = (long long)lb * 256 + threadIdx.x; i < pn4; i += (long long)nb * 256) {
        if (i < n4) {
            float4 v = w4[i];
            q[i] = pack4(rintf(v.x * scale), rintf(v.y * scale),
                         rintf(v.z * scale), rintf(v.w * scale), -1.f, 1.f);
        } else {
            q[i] = 0;  // zero-pad W3 rows 2000..2047
        }
    }
}

// ---------------- input activation quantization (D = 1024) ----------------
__global__ __launch_bounds__(256) void actquant_kernel(const float* __restrict__ x,
                                                       int* __restrict__ q,
                                                       float* __restrict__ inv_s) {
    __shared__ float s4[4];
    int row = blockIdx.x;
    const float4* xr = (const float4*)(x + (size_t)row * 1024);
    float4 v = xr[threadIdx.x];
    float m = fmaxf(fmaxf(fabsf(v.x), fabsf(v.y)), fmaxf(fabsf(v.z), fabsf(v.w)));
    m = blk_max(m, s4);
    m = fmaxf(m, EPS);
    float scale = 127.f / m;
    if (threadIdx.x == 0) inv_s[row] = m / 127.f;
    q[(size_t)row * 256 + threadIdx.x] =
        pack4(rintf(v.x * scale), rintf(v.y * scale),
              rintf(v.z * scale), rintf(v.w * scale), -128.f, 127.f);
}

// ---------------- fused LayerNorm + SiLU + act quant, bf16 input (H = 4096) ------------
__global__ __launch_bounds__(256) void ln_silu_quant_kernel(const ushort* __restrict__ h,
                                                            const float* __restrict__ g,
                                                            const float* __restrict__ b,
                                                            int* __restrict__ q,
                                                            float* __restrict__ inv_s) {
    __shared__ float s8[8];
    int row = blockIdx.x;
    int t = threadIdx.x;
    const uint4* hr = (const uint4*)(h + (size_t)row * 4096);
    uint4 p0 = hr[t * 2], p1 = hr[t * 2 + 1];  // 16 bf16 elems per thread
    float f[16];
    f[0] = bflo(p0.x); f[1] = bfhi(p0.x); f[2] = bflo(p0.y); f[3] = bfhi(p0.y);
    f[4] = bflo(p0.z); f[5] = bfhi(p0.z); f[6] = bflo(p0.w); f[7] = bfhi(p0.w);
    f[8] = bflo(p1.x); f[9] = bfhi(p1.x); f[10] = bflo(p1.y); f[11] = bfhi(p1.y);
    f[12] = bflo(p1.z); f[13] = bfhi(p1.z); f[14] = bflo(p1.w); f[15] = bfhi(p1.w);
    float sum = 0.f, sq = 0.f;
    #pragma unroll
    for (int i = 0; i < 16; i++) { sum += f[i]; sq += f[i] * f[i]; }
    blk_sum2(sum, sq, s8);
    float mu = sum * (1.f / 4096.f);
    float var = sq * (1.f / 4096.f) - mu * mu;
    float rs = rsqrtf(var + EPS);
    const float4* g4 = (const float4*)g;
    const float4* b4 = (const float4*)b;
    float amax = 0.f;
    #pragma unroll
    for (int i = 0; i < 4; i++) {
        float4 gg = g4[t * 4 + i];
        float4 bb = b4[t * 4 + i];
        float y0 = (f[i * 4 + 0] - mu) * rs * gg.x + bb.x;
        float y1 = (f[i * 4 + 1] - mu) * rs * gg.y + bb.y;
        float y2 = (f[i * 4 + 2] - mu) * rs * gg.z + bb.z;
        float y3 = (f[i * 4 + 3] - mu) * rs * gg.w + bb.w;
        f[i * 4 + 0] = y0 / (1.f + expf(-y0));
        f[i * 4 + 1] = y1 / (1.f + expf(-y1));
        f[i * 4 + 2] = y2 / (1.f + expf(-y2));
        f[i * 4 + 3] = y3 / (1.f + expf(-y3));
    }
    #pragma unroll
    for (int i = 0; i < 16; i++) amax = fmaxf(amax, fabsf(f[i]));
    amax = blk_max(amax, s8);
    amax = fmaxf(amax, EPS);
    float scale = 127.f / amax;
    if (t == 0) inv_s[row] = amax / 127.f;
    int4 o;
    o.x = pack4(rintf(f[0] * scale), rintf(f[1] * scale), rintf(f[2] * scale), rintf(f[3] * scale), -128.f, 127.f);
    o.y = pack4(rintf(f[4] * scale), rintf(f[5] * scale), rintf(f[6] * scale), rintf(f[7] * scale), -128.f, 127.f);
    o.z = pack4(rintf(f[8] * scale), rintf(f[9] * scale), rintf(f[10] * scale), rintf(f[11] * scale), -128.f, 127.f);
    o.w = pack4(rintf(f[12] * scale), rintf(f[13] * scale), rintf(f[14] * scale), rintf(f[15] * scale), -128.f, 127.f);
    ((int4*)((char*)q + (size_t)row * 4096))[t] = o;
}

// ---------------- i8 MFMA GEMM: C[b,o] = sum_k A[b,k]*B[o,k] ----------------
// 128x128 tile, BK=128 (32 KB LDS), XOR-swizzled rows, 16x16x64 MFMA,
// 4 waves each computing a 64x64 quadrant (4x4 of 16x16x64).
// Swizzle: element (row, c) stored at LDS col c ^ (16*(row&7)); implemented by
// permuting the per-lane GLOBAL source address (LDS side must stay lane*16).
__device__ __forceinline__ void load_lds16(const void* g, void* l) {
    __builtin_amdgcn_global_load_lds((__attribute__((address_space(1))) void*)(g),
                                     (__attribute__((address_space(3))) void*)(l), 16, 0, 0);
}

template <int MODE>  // 0: write bf16 h[gr*4096+gc]; 1: final sigmoid epilogue into d_out
__global__ __launch_bounds__(256, 2) void gemm_i8_kernel(
    const char* __restrict__ A, const char* __restrict__ B,
    const float* __restrict__ inv_s, const float* __restrict__ wsum, float invWN,
    int K, void* __restrict__ outp) {
    __shared__ __align__(16) char lA[128 * 128];
    __shared__ __align__(16) char lB[128 * 128];
    const int t = threadIdx.x;
    const int lane = t & 63;
    const int wave = t >> 6;
    const int bm = blockIdx.y * 128, bn = blockIdx.x * 128;
    const int wr = (wave >> 1) * 64, wc = (wave & 1) * 64;

    int32x4 acc[4][4] = {};

    // staging: LDS linear slot li = j*4096 + t*16 -> row = j*32 + (t>>3),
    // storage col = (t&7)*16; global col = storage col ^ 16*(row&7) (row&7 == r0&7)
    const int r0 = t >> 3;
    const int c0 = (t & 7) * 16;
    const int gcol = c0 ^ (16 * (r0 & 7));
    const char* gA = A + (size_t)(bm + r0) * K + gcol;
    const char* gB = B + (size_t)(bn + r0) * K + gcol;
    char* sA = lA + t * 16;
    char* sB = lB + t * 16;

    const int fr = lane & 15;
    const int fq = lane >> 4;
    const int swz = 16 * (fr & 7);  // (wr + mt*16 + fr) & 7 == fr & 7

    for (int k0 = 0; k0 < K; k0 += 128) {
        #pragma unroll
        for (int j = 0; j < 4; j++)
            load_lds16(gA + (size_t)(j * 32) * K + k0, sA + j * 4096);
        #pragma unroll
        for (int j = 0; j < 4; j++)
            load_lds16(gB + (size_t)(j * 32) * K + k0, sB + j * 4096);
        __syncthreads();

        #pragma unroll
        for (int ks = 0; ks < 2; ks++) {
            const int col = (ks * 64 + fq * 16) ^ swz;
            int32x4 af[4], bf[4];
            #pragma unroll
            for (int mt = 0; mt < 4; mt++)
                af[mt] = *(const int32x4*)(lA + (wr + mt * 16 + fr) * 128 + col);
            #pragma unroll
            for (int nt = 0; nt < 4; nt++)
                bf[nt] = *(const int32x4*)(lB + (wc + nt * 16 + fr) * 128 + col);
            #pragma unroll
            for (int mt = 0; mt < 4; mt++) {
                #pragma unroll
                for (int nt = 0; nt < 4; nt++) {
                    acc[mt][nt] = __builtin_amdgcn_mfma_i32_16x16x64_i8(af[mt], bf[nt],
                                                                        acc[mt][nt], 0, 0, 0);
                }
            }
        }
        __syncthreads();
    }

    // epilogue: C/D layout col = lane&15, row = (lane>>4)*4 + reg
    const float wmean = fmaxf(wsum[0] * invWN, EPS);
    #pragma unroll
    for (int mt = 0; mt < 4; mt++) {
        #pragma unroll
        for (int rg = 0; rg < 4; rg++) {
            int gr = bm + wr + mt * 16 + fq * 4 + rg;
            float rowscale = inv_s[gr] * wmean;
            #pragma unroll
            for (int nt = 0; nt < 4; nt++) {
                int gc = bn + wc + nt * 16 + fr;
                float v = (float)acc[mt][nt][rg] * rowscale;
                if (MODE == 0) {
                    ((__hip_bfloat16*)outp)[(size_t)gr * 4096 + gc] = __float2bfloat16(v);
                } else {
                    if (gc < 2000) {
                        float sg = 1.f / (1.f + expf(-v));
                        float* out = (float*)outp;
                        if (gc < 1000)
                            out[(size_t)gr * 1000 + gc] = sg * 999.f + 1.f;
                        else
                            out[(size_t)4096 * 1000 + (size_t)gr * 1000 + (gc - 1000)] =
                                sg * 100.f;
                    }
                }
            }
        }
    }
}

// ---------------- host launcher ----------------
extern "C" void kernel_launch(void* const* d_in, const int* in_sizes, int n_in,
                              void* d_out, int out_size, void* d_ws, size_t ws_size,
                              hipStream_t stream) {
    const float* x  = (const float*)d_in[0];
    const float* W0 = (const float*)d_in[1];
    const float* W1 = (const float*)d_in[2];
    const float* W2 = (const float*)d_in[3];
    const float* W3 = (const float*)d_in[4];
    const float* g0 = (const float*)d_in[5];
    const float* b0 = (const float*)d_in[6];
    const float* g1 = (const float*)d_in[7];
    const float* b1 = (const float*)d_in[8];
    const float* g2 = (const float*)d_in[9];
    const float* b2 = (const float*)d_in[10];
    float* out = (float*)d_out;

    char* ws = (char*)d_ws;
    size_t off = 0;
    auto alloc = [&](size_t bytes) -> char* {
        char* p = ws + off;
        off = (off + bytes + 255) & ~(size_t)255;
        return p;
    };
    float* sums = (float*)alloc(4 * sizeof(float));
    float* inv0 = (float*)alloc(4096 * 4);
    float* inv1 = (float*)alloc(4096 * 4);
    float* inv2 = (float*)alloc(4096 * 4);
    float* inv3 = (float*)alloc(4096 * 4);
    char* wq0 = alloc(4096ll * 1024);
    char* wq1 = alloc(4096ll * 4096);
    char* wq2 = alloc(4096ll * 4096);
    char* wq3 = alloc(2048ll * 4096);   // padded to 2048 rows
    char* a0  = alloc(4096ll * 1024);
    char* a1  = alloc(4096ll * 4096);
    char* a2  = alloc(4096ll * 4096);
    char* h   = alloc(4096ll * 4096 * 2);  // bf16 intermediate
    char* a3 = a1;  // a1 dead after GEMM1; safe sequential reuse

    hipMemsetAsync(sums, 0, 4 * sizeof(float), stream);

    absmean_all_kernel<<<6144, 256, 0, stream>>>(W0, W1, W2, W3, sums);
    actquant_kernel<<<4096, 256, 0, stream>>>(x, (int*)a0, inv0);
    wquant_all_kernel<<<6144, 256, 0, stream>>>(W0, W1, W2, W3, (int*)wq0, (int*)wq1,
                                                (int*)wq2, (int*)wq3, sums);

    gemm_i8_kernel<0><<<dim3(32, 32), 256, 0, stream>>>(a0, wq0, inv0, sums + 0,
                                                        1.f / 4194304.f, 1024, h);
    ln_silu_quant_kernel<<<4096, 256, 0, stream>>>((const ushort*)h, g0, b0, (int*)a1, inv1);

    gemm_i8_kernel<0><<<dim3(32, 32), 256, 0, stream>>>(a1, wq1, inv1, sums + 1,
                                                        1.f / 16777216.f, 4096, h);
    ln_silu_quant_kernel<<<4096, 256, 0, stream>>>((const ushort*)h, g1, b1, (int*)a2, inv2);

    gemm_i8_kernel<0><<<dim3(32, 32), 256, 0, stream>>>(a2, wq2, inv2, sums + 2,
                                                        1.f / 16777216.f, 4096, h);
    ln_silu_quant_kernel<<<4096, 256, 0, stream>>>((const ushort*)h, g2, b2, (int*)a3, inv3);

    gemm_i8_kernel<1><<<dim3(16, 32), 256, 0, stream>>>(a3, wq3, inv3, sums + 3,
                                                        1.f / 8192000.f, 4096, out);
}